// Round 1
// baseline (1591.123 us; speedup 1.0000x reference)
//
#include <hip/hip_runtime.h>

#define NUSERS 100000
#define NITEMS 50000
#define NNODES 150000   // NUSERS + NITEMS
#define EMB 64
#define NEDGES 4800000
#define OUTC 192        // 3 * EMB concatenated output columns
#define NEG_SLOPE 0.01f

// ---------------- ego0 build: gather user/item embeddings into out cols 0:64
__global__ void build_ego(const int* __restrict__ ui, const int* __restrict__ ii,
                          const float* __restrict__ uemb, const float* __restrict__ iemb,
                          float* __restrict__ out) {
    int gid = blockIdx.x * blockDim.x + threadIdx.x;   // one float4 per thread
    int r = gid >> 4, p = gid & 15;
    if (r >= NNODES) return;
    const float* src = (r < NUSERS) ? (uemb + (size_t)ui[r] * EMB)
                                    : (iemb + (size_t)ii[r - NUSERS] * EMB);
    float4 v = ((const float4*)src)[p];
    *(float4*)(out + (size_t)r * OUTC + p * 4) = v;
}

// ---------------- CSR build ----------------
__global__ void count_rows(const int* __restrict__ rows, int* __restrict__ counts) {
    int gid = blockIdx.x * blockDim.x + threadIdx.x;
    if (gid < NEDGES) atomicAdd(&counts[rows[gid]], 1);
}

// inclusive scan of 1024-chunks -> rowptr[i+1]; block totals to blksum
__global__ void scan_chunk(const int* __restrict__ counts, int* __restrict__ rowptr,
                           int* __restrict__ blksum, int n) {
    __shared__ int buf[1024];
    int tid = threadIdx.x;
    int gid = blockIdx.x * 1024 + tid;
    int v = (gid < n) ? counts[gid] : 0;
    buf[tid] = v;
    __syncthreads();
    for (int off = 1; off < 1024; off <<= 1) {
        int t = (tid >= off) ? buf[tid - off] : 0;
        __syncthreads();
        buf[tid] += t;
        __syncthreads();
    }
    if (gid < n) rowptr[gid + 1] = buf[tid];
    if (tid == 1023) blksum[blockIdx.x] = buf[tid];
}

// exclusive scan of block sums (n <= 256), single block
__global__ void scan_sums(int* __restrict__ blksum, int n) {
    __shared__ int buf[256];
    int tid = threadIdx.x;
    int v = (tid < n) ? blksum[tid] : 0;
    buf[tid] = v;
    __syncthreads();
    for (int off = 1; off < 256; off <<= 1) {
        int t = (tid >= off) ? buf[tid - off] : 0;
        __syncthreads();
        buf[tid] += t;
        __syncthreads();
    }
    if (tid < n) blksum[tid] = buf[tid] - v;  // exclusive
}

__global__ void add_offsets(int* __restrict__ rowptr, const int* __restrict__ blksum, int n) {
    int gid = blockIdx.x * 1024 + threadIdx.x;
    if (gid < n) rowptr[gid + 1] += blksum[blockIdx.x];
    if (gid == 0) rowptr[0] = 0;
}

__global__ void fill_csr(const int* __restrict__ rows, const int* __restrict__ cols,
                         const float* __restrict__ vals, const int* __restrict__ rowptr,
                         int* __restrict__ cursor, int* __restrict__ ccol,
                         float* __restrict__ cval) {
    int gid = blockIdx.x * blockDim.x + threadIdx.x;
    if (gid >= NEDGES) return;
    int r = rows[gid];
    int pos = atomicAdd(&cursor[r], 1);
    int idx = rowptr[r] + pos;
    ccol[idx] = cols[gid];
    cval[idx] = vals[gid];
}

// ---------------- SpMM: side = A @ ego ----------------
// one wave per row; lane = dim. ego read from out (row stride OUTC) at column
// offset egoBase. cols/vals batch-loaded coalesced, broadcast via shfl.
__global__ void spmm(const int* __restrict__ rowptr, const int* __restrict__ ccol,
                     const float* __restrict__ cval, const float* __restrict__ ego,
                     float* __restrict__ side) {
    int wid  = (blockIdx.x * blockDim.x + threadIdx.x) >> 6;  // row
    int lane = threadIdx.x & 63;
    if (wid >= NNODES) return;
    int s = rowptr[wid], e = rowptr[wid + 1];
    float acc = 0.f;
    for (int base = s; base < e; base += 64) {
        int nb = e - base; if (nb > 64) nb = 64;
        int   c = 0;
        float v = 0.f;
        if (base + lane < e) { c = ccol[base + lane]; v = cval[base + lane]; }
        for (int k = 0; k < nb; ++k) {
            int   ck = __shfl(c, k);
            float vk = __shfl(v, k);
            acc = fmaf(vk, ego[(size_t)ck * OUTC + lane], acc);
        }
    }
    side[(size_t)wid * EMB + lane] = acc;
}

// ---------------- fused dense: egoNew = LReLU(side@Wg^T+bg) + LReLU((ego*side)@Wb^T+bb)
// 1024 threads = 16 waves = 16 rows per block; W staged transposed in LDS (+1 pad).
__global__ __launch_bounds__(1024) void dense_layer(
        const float* __restrict__ side, const float* __restrict__ egoPrev,
        float* __restrict__ egoNew,
        const float* __restrict__ Wg, const float* __restrict__ bg,
        const float* __restrict__ Wb, const float* __restrict__ bb) {
    __shared__ float WgT[64 * 65];
    __shared__ float WbT[64 * 65];
    int tid = threadIdx.x;
    for (int i = tid; i < 4096; i += 1024) {
        int r = i >> 6, c = i & 63;            // W[r][c]
        WgT[c * 65 + r] = Wg[i];
        WbT[c * 65 + r] = Wb[i];
    }
    __syncthreads();
    int row  = blockIdx.x * 16 + (tid >> 6);
    int lane = tid & 63;
    if (row >= NNODES) return;
    float s = side[(size_t)row * EMB + lane];
    float eg = egoPrev[(size_t)row * OUTC + lane];
    float p = s * eg;
    float accg = bg[lane], accb = bb[lane];
    #pragma unroll
    for (int k = 0; k < 64; ++k) {
        float sk = __shfl(s, k);
        float pk = __shfl(p, k);
        accg = fmaf(sk, WgT[k * 65 + lane], accg);
        accb = fmaf(pk, WbT[k * 65 + lane], accb);
    }
    accg = (accg > 0.f) ? accg : NEG_SLOPE * accg;
    accb = (accb > 0.f) ? accb : NEG_SLOPE * accb;
    egoNew[(size_t)row * OUTC + lane] = accg + accb;
}

extern "C" void kernel_launch(void* const* d_in, const int* in_sizes, int n_in,
                              void* d_out, int out_size, void* d_ws, size_t ws_size,
                              hipStream_t stream) {
    const int*   ui   = (const int*)  d_in[0];
    const int*   ii   = (const int*)  d_in[1];
    const int*   rows = (const int*)  d_in[2];
    const int*   cols = (const int*)  d_in[3];
    const float* vals = (const float*)d_in[4];
    const float* uemb = (const float*)d_in[5];
    const float* iemb = (const float*)d_in[6];
    const float* Wg0 = (const float*)d_in[7],  *bg0 = (const float*)d_in[8];
    const float* Wb0 = (const float*)d_in[9],  *bb0 = (const float*)d_in[10];
    const float* Wg1 = (const float*)d_in[11], *bg1 = (const float*)d_in[12];
    const float* Wb1 = (const float*)d_in[13], *bb1 = (const float*)d_in[14];
    float* out = (float*)d_out;

    char* ws = (char*)d_ws;
    float* side   = (float*)ws; ws += (size_t)NNODES * EMB * 4;
    int*   ccol   = (int*)  ws; ws += (size_t)NEDGES * 4;
    float* cval   = (float*)ws; ws += (size_t)NEDGES * 4;
    int*   rowptr = (int*)  ws; ws += (size_t)(NNODES + 1) * 4;
    int*   counts = (int*)  ws; ws += (size_t)NNODES * 4;
    int*   blksum = (int*)  ws; ws += 256 * 4;

    const int NBLK = (NNODES + 1023) / 1024;  // 147

    // ego0 -> out cols [0,64)
    build_ego<<<(NNODES * 16 + 255) / 256, 256, 0, stream>>>(ui, ii, uemb, iemb, out);

    // CSR build (once, reused for both layers)
    hipMemsetAsync(counts, 0, (size_t)NNODES * 4, stream);
    count_rows<<<(NEDGES + 255) / 256, 256, 0, stream>>>(rows, counts);
    scan_chunk<<<NBLK, 1024, 0, stream>>>(counts, rowptr, blksum, NNODES);
    scan_sums<<<1, 256, 0, stream>>>(blksum, NBLK);
    add_offsets<<<NBLK, 1024, 0, stream>>>(rowptr, blksum, NNODES);
    hipMemsetAsync(counts, 0, (size_t)NNODES * 4, stream);  // reuse as cursor
    fill_csr<<<(NEDGES + 255) / 256, 256, 0, stream>>>(rows, cols, vals, rowptr, counts, ccol, cval);

    // layer 0: side = A @ ego0 ; ego1 -> out cols [64,128)
    spmm<<<(NNODES + 3) / 4, 256, 0, stream>>>(rowptr, ccol, cval, out + 0, side);
    dense_layer<<<(NNODES + 15) / 16, 1024, 0, stream>>>(side, out + 0, out + 64,
                                                         Wg0, bg0, Wb0, bb0);
    // layer 1: side = A @ ego1 ; ego2 -> out cols [128,192)
    spmm<<<(NNODES + 3) / 4, 256, 0, stream>>>(rowptr, ccol, cval, out + 64, side);
    dense_layer<<<(NNODES + 15) / 16, 1024, 0, stream>>>(side, out + 64, out + 128,
                                                         Wg1, bg1, Wb1, bb1);
}

// Round 2
// 1014.785 us; speedup vs baseline: 1.5679x; 1.5679x over previous
//
#include <hip/hip_runtime.h>

#define NUSERS 100000
#define NITEMS 50000
#define NNODES 150000   // NUSERS + NITEMS
#define EMB 64
#define NEDGES 4800000
#define OUTC 192        // 3 * EMB concatenated output columns
#define NEG_SLOPE 0.01f

// ---------------- ego0 build: gather user/item embeddings into out cols 0:64
__global__ void build_ego(const int* __restrict__ ui, const int* __restrict__ ii,
                          const float* __restrict__ uemb, const float* __restrict__ iemb,
                          float* __restrict__ out) {
    int gid = blockIdx.x * blockDim.x + threadIdx.x;   // one float4 per thread
    int r = gid >> 4, p = gid & 15;
    if (r >= NNODES) return;
    const float* src = (r < NUSERS) ? (uemb + (size_t)ui[r] * EMB)
                                    : (iemb + (size_t)ii[r - NUSERS] * EMB);
    float4 v = ((const float4*)src)[p];
    *(float4*)(out + (size_t)r * OUTC + p * 4) = v;
}

// ---------------- CSR build ----------------
// pass 1: count rows AND record each edge's within-row position (removes
// atomics from the fill pass; pos written coalesced)
__global__ void count_pos(const int* __restrict__ rows, int* __restrict__ counts,
                          int* __restrict__ pos) {
    int gid = blockIdx.x * blockDim.x + threadIdx.x;
    if (gid < NEDGES) pos[gid] = atomicAdd(&counts[rows[gid]], 1);
}

// inclusive scan of 1024-chunks -> rowptr[i+1]; block totals to blksum
__global__ void scan_chunk(const int* __restrict__ counts, int* __restrict__ rowptr,
                           int* __restrict__ blksum, int n) {
    __shared__ int buf[1024];
    int tid = threadIdx.x;
    int gid = blockIdx.x * 1024 + tid;
    int v = (gid < n) ? counts[gid] : 0;
    buf[tid] = v;
    __syncthreads();
    for (int off = 1; off < 1024; off <<= 1) {
        int t = (tid >= off) ? buf[tid - off] : 0;
        __syncthreads();
        buf[tid] += t;
        __syncthreads();
    }
    if (gid < n) rowptr[gid + 1] = buf[tid];
    if (tid == 1023) blksum[blockIdx.x] = buf[tid];
}

// exclusive scan of block sums (n <= 256), single block
__global__ void scan_sums(int* __restrict__ blksum, int n) {
    __shared__ int buf[256];
    int tid = threadIdx.x;
    int v = (tid < n) ? blksum[tid] : 0;
    buf[tid] = v;
    __syncthreads();
    for (int off = 1; off < 256; off <<= 1) {
        int t = (tid >= off) ? buf[tid - off] : 0;
        __syncthreads();
        buf[tid] += t;
        __syncthreads();
    }
    if (tid < n) blksum[tid] = buf[tid] - v;  // exclusive
}

__global__ void add_offsets(int* __restrict__ rowptr, const int* __restrict__ blksum, int n) {
    int gid = blockIdx.x * 1024 + threadIdx.x;
    if (gid < n) rowptr[gid + 1] += blksum[blockIdx.x];
    if (gid == 0) rowptr[0] = 0;
}

// pass 2: atomic-free scatter of packed (col, val) int2
__global__ void fill_csr(const int* __restrict__ rows, const int* __restrict__ cols,
                         const float* __restrict__ vals, const int* __restrict__ pos,
                         const int* __restrict__ rowptr, int2* __restrict__ csr) {
    int gid = blockIdx.x * blockDim.x + threadIdx.x;
    if (gid >= NEDGES) return;
    int r = rows[gid];
    int idx = rowptr[r] + pos[gid];
    csr[idx] = make_int2(cols[gid], __float_as_int(vals[gid]));
}

// ---------------- fused SpMM + dense layer ----------------
// one wave per row. Phase 1: side_row = sum over edges of val * ego[col]
//   (4 edges in flight, each lane loads float4: wave reads 1KB/instr)
// Phase 2: egoNew = LReLU(side@Wg^T+bg) + LReLU((ego*side)@Wb^T+bb)
//   via LDS-staged transposed W, broadcast shfl loop.
__global__ __launch_bounds__(512) void spmm_fused(
        const int* __restrict__ rowptr, const int2* __restrict__ csr,
        const float* __restrict__ egoPrev, float* __restrict__ egoNew,
        const float* __restrict__ Wg, const float* __restrict__ bg,
        const float* __restrict__ Wb, const float* __restrict__ bb) {
    __shared__ float WgT[64 * 65];
    __shared__ float WbT[64 * 65];
    int tid = threadIdx.x;
    for (int i = tid; i < 4096; i += 512) {
        int r = i >> 6, c = i & 63;            // W[r][c]
        WgT[c * 65 + r] = Wg[i];
        WbT[c * 65 + r] = Wb[i];
    }
    __syncthreads();
    int lane = tid & 63;
    int row = blockIdx.x * 8 + (tid >> 6);
    if (row >= NNODES) return;

    int s = rowptr[row], e = rowptr[row + 1];
    int esub = lane >> 4;        // which of 4 concurrent edges this lane serves
    int dg   = lane & 15;        // dim group (float4 index)
    float4 acc = make_float4(0.f, 0.f, 0.f, 0.f);
    for (int base = s; base < e; base += 64) {
        int nb = e - base; if (nb > 64) nb = 64;
        int2 cv = make_int2(0, 0);
        if (base + lane < e) cv = csr[base + lane];
        int nIter = (nb + 3) >> 2;
        for (int k = 0; k < nIter; ++k) {
            int src = 4 * k + esub;
            int   ck = __shfl(cv.x, src);
            float vk = __uint_as_float((unsigned)__shfl(cv.y, src)); // 0 for src>=nb
            float4 g = *(const float4*)(egoPrev + (size_t)ck * OUTC + dg * 4);
            acc.x = fmaf(vk, g.x, acc.x);
            acc.y = fmaf(vk, g.y, acc.y);
            acc.z = fmaf(vk, g.z, acc.z);
            acc.w = fmaf(vk, g.w, acc.w);
        }
    }
    // reduce the 4 edge-subgroups: lanes {l, l^16, l^32, l^48} hold same dims
    acc.x += __shfl_xor(acc.x, 16); acc.y += __shfl_xor(acc.y, 16);
    acc.z += __shfl_xor(acc.z, 16); acc.w += __shfl_xor(acc.w, 16);
    acc.x += __shfl_xor(acc.x, 32); acc.y += __shfl_xor(acc.y, 32);
    acc.z += __shfl_xor(acc.z, 32); acc.w += __shfl_xor(acc.w, 32);
    // redistribute: lane j wants dim j = element (j&3) of group (j>>2),
    // held by lane (j>>2) (any lane with l&15 == j>>2)
    int srcl = lane >> 2;
    float t0 = __shfl(acc.x, srcl), t1 = __shfl(acc.y, srcl);
    float t2 = __shfl(acc.z, srcl), t3 = __shfl(acc.w, srcl);
    int e2 = lane & 3;
    float sv = (e2 == 0) ? t0 : (e2 == 1) ? t1 : (e2 == 2) ? t2 : t3;

    // dense epilogue
    float eg = egoPrev[(size_t)row * OUTC + lane];
    float p  = sv * eg;
    float accg = bg[lane], accb = bb[lane];
    #pragma unroll
    for (int k = 0; k < 64; ++k) {
        float sk = __shfl(sv, k);
        float pk = __shfl(p, k);
        accg = fmaf(sk, WgT[k * 65 + lane], accg);
        accb = fmaf(pk, WbT[k * 65 + lane], accb);
    }
    accg = (accg > 0.f) ? accg : NEG_SLOPE * accg;
    accb = (accb > 0.f) ? accb : NEG_SLOPE * accb;
    egoNew[(size_t)row * OUTC + lane] = accg + accb;
}

extern "C" void kernel_launch(void* const* d_in, const int* in_sizes, int n_in,
                              void* d_out, int out_size, void* d_ws, size_t ws_size,
                              hipStream_t stream) {
    const int*   ui   = (const int*)  d_in[0];
    const int*   ii   = (const int*)  d_in[1];
    const int*   rows = (const int*)  d_in[2];
    const int*   cols = (const int*)  d_in[3];
    const float* vals = (const float*)d_in[4];
    const float* uemb = (const float*)d_in[5];
    const float* iemb = (const float*)d_in[6];
    const float* Wg0 = (const float*)d_in[7],  *bg0 = (const float*)d_in[8];
    const float* Wb0 = (const float*)d_in[9],  *bb0 = (const float*)d_in[10];
    const float* Wg1 = (const float*)d_in[11], *bg1 = (const float*)d_in[12];
    const float* Wb1 = (const float*)d_in[13], *bb1 = (const float*)d_in[14];
    float* out = (float*)d_out;

    char* ws = (char*)d_ws;
    int2*  csr    = (int2*)ws; ws += (size_t)NEDGES * 8;
    int*   pos    = (int*) ws; ws += (size_t)NEDGES * 4;
    int*   rowptr = (int*) ws; ws += (size_t)(NNODES + 1) * 4;
    int*   counts = (int*) ws; ws += (size_t)NNODES * 4;
    int*   blksum = (int*) ws; ws += 256 * 4;

    const int NBLK = (NNODES + 1023) / 1024;  // 147

    // ego0 -> out cols [0,64)
    build_ego<<<(NNODES * 16 + 255) / 256, 256, 0, stream>>>(ui, ii, uemb, iemb, out);

    // CSR build (once, reused for both layers)
    hipMemsetAsync(counts, 0, (size_t)NNODES * 4, stream);
    count_pos<<<(NEDGES + 255) / 256, 256, 0, stream>>>(rows, counts, pos);
    scan_chunk<<<NBLK, 1024, 0, stream>>>(counts, rowptr, blksum, NNODES);
    scan_sums<<<1, 256, 0, stream>>>(blksum, NBLK);
    add_offsets<<<NBLK, 1024, 0, stream>>>(rowptr, blksum, NNODES);
    fill_csr<<<(NEDGES + 255) / 256, 256, 0, stream>>>(rows, cols, vals, pos, rowptr, csr);

    // layer 0: ego1 -> out cols [64,128)
    spmm_fused<<<(NNODES + 7) / 8, 512, 0, stream>>>(rowptr, csr, out + 0, out + 64,
                                                     Wg0, bg0, Wb0, bb0);
    // layer 1: ego2 -> out cols [128,192)
    spmm_fused<<<(NNODES + 7) / 8, 512, 0, stream>>>(rowptr, csr, out + 64, out + 128,
                                                     Wg1, bg1, Wb1, bb1);
}

// Round 3
// 1000.714 us; speedup vs baseline: 1.5900x; 1.0141x over previous
//
#include <hip/hip_runtime.h>

#define NUSERS 100000
#define NITEMS 50000
#define NNODES 150000   // NUSERS + NITEMS
#define EMB 64
#define NEDGES 4800000
#define OUTC 192        // 3 * EMB concatenated output columns
#define NEG_SLOPE 0.01f

// ---------------- ego0 build: gather user/item embeddings into out cols 0:64
__global__ void build_ego(const int* __restrict__ ui, const int* __restrict__ ii,
                          const float* __restrict__ uemb, const float* __restrict__ iemb,
                          float* __restrict__ out) {
    int gid = blockIdx.x * blockDim.x + threadIdx.x;   // one float4 per thread
    int r = gid >> 4, p = gid & 15;
    if (r >= NNODES) return;
    const float* src = (r < NUSERS) ? (uemb + (size_t)ui[r] * EMB)
                                    : (iemb + (size_t)ii[r - NUSERS] * EMB);
    float4 v = ((const float4*)src)[p];
    *(float4*)(out + (size_t)r * OUTC + p * 4) = v;
}

// ---------------- CSR build ----------------
// pass 1: count rows AND record each edge's within-row position (removes
// atomics from the fill pass; pos written coalesced)
__global__ void count_pos(const int* __restrict__ rows, int* __restrict__ counts,
                          int* __restrict__ pos) {
    int gid = blockIdx.x * blockDim.x + threadIdx.x;
    if (gid < NEDGES) pos[gid] = atomicAdd(&counts[rows[gid]], 1);
}

// inclusive scan of 1024-chunks -> rowptr[i+1]; block totals to blksum
__global__ void scan_chunk(const int* __restrict__ counts, int* __restrict__ rowptr,
                           int* __restrict__ blksum, int n) {
    __shared__ int buf[1024];
    int tid = threadIdx.x;
    int gid = blockIdx.x * 1024 + tid;
    int v = (gid < n) ? counts[gid] : 0;
    buf[tid] = v;
    __syncthreads();
    for (int off = 1; off < 1024; off <<= 1) {
        int t = (tid >= off) ? buf[tid - off] : 0;
        __syncthreads();
        buf[tid] += t;
        __syncthreads();
    }
    if (gid < n) rowptr[gid + 1] = buf[tid];
    if (tid == 1023) blksum[blockIdx.x] = buf[tid];
}

// exclusive scan of block sums (n <= 256), single block
__global__ void scan_sums(int* __restrict__ blksum, int n) {
    __shared__ int buf[256];
    int tid = threadIdx.x;
    int v = (tid < n) ? blksum[tid] : 0;
    buf[tid] = v;
    __syncthreads();
    for (int off = 1; off < 256; off <<= 1) {
        int t = (tid >= off) ? buf[tid - off] : 0;
        __syncthreads();
        buf[tid] += t;
        __syncthreads();
    }
    if (tid < n) blksum[tid] = buf[tid] - v;  // exclusive
}

__global__ void add_offsets(int* __restrict__ rowptr, const int* __restrict__ blksum, int n) {
    int gid = blockIdx.x * 1024 + threadIdx.x;
    if (gid < n) rowptr[gid + 1] += blksum[blockIdx.x];
    if (gid == 0) rowptr[0] = 0;
}

// pass 2: atomic-free scatter of packed (col, val) int2
__global__ void fill_csr(const int* __restrict__ rows, const int* __restrict__ cols,
                         const float* __restrict__ vals, const int* __restrict__ pos,
                         const int* __restrict__ rowptr, int2* __restrict__ csr) {
    int gid = blockIdx.x * blockDim.x + threadIdx.x;
    if (gid >= NEDGES) return;
    int r = rows[gid];
    int idx = rowptr[r] + pos[gid];
    csr[idx] = make_int2(cols[gid], __float_as_int(vals[gid]));
}

// ---------------- fused SpMM + dense layer ----------------
// one wave per row. Phase 1: side_row = sum over edges of val * ego[col]
//   16 edges in flight: each lane issues 4 independent float4 gathers per
//   inner step (4x MLP vs previous version).
// Phase 2: egoNew = LReLU(side@Wg^T+bg) + LReLU((ego*side)@Wb^T+bb)
//   LDS-staged transposed W; 4-way split accumulators (dep chain 64 -> 16).
__global__ __launch_bounds__(512) void spmm_fused(
        const int* __restrict__ rowptr, const int2* __restrict__ csr,
        const float* __restrict__ egoPrev, float* __restrict__ egoNew,
        const float* __restrict__ Wg, const float* __restrict__ bg,
        const float* __restrict__ Wb, const float* __restrict__ bb) {
    __shared__ float WgT[64 * 65];
    __shared__ float WbT[64 * 65];
    int tid = threadIdx.x;
    for (int i = tid; i < 4096; i += 512) {
        int r = i >> 6, c = i & 63;            // W[r][c]
        WgT[c * 65 + r] = Wg[i];
        WbT[c * 65 + r] = Wb[i];
    }
    __syncthreads();
    int lane = tid & 63;
    int row = blockIdx.x * 8 + (tid >> 6);
    if (row >= NNODES) return;

    float biasg = bg[lane], biasb = bb[lane];  // hoisted above gather
    int s = rowptr[row], e = rowptr[row + 1];
    int esub = lane >> 4;        // edge-subgroup 0..3
    int dg   = lane & 15;        // dim group (float4 index)
    size_t dgo = (size_t)dg * 4;
    float4 acc = make_float4(0.f, 0.f, 0.f, 0.f);
    for (int base = s; base < e; base += 64) {
        int2 cv = make_int2(0, 0);
        if (base + lane < e) cv = csr[base + lane];
        int nb = e - base; if (nb > 64) nb = 64;
        int mMax = (nb + 3) >> 2;            // 4 edges per m step
        for (int m = 0; m < mMax; m += 4) {
            // 4 independent gathers in flight per lane (edges m..m+3 of subgroup)
            int s0 = 4 * m + esub, s1 = s0 + 4, s2 = s1 + 4, s3 = s2 + 4;
            int c0 = __shfl(cv.x, s0), c1 = __shfl(cv.x, s1);
            int c2 = __shfl(cv.x, s2), c3 = __shfl(cv.x, s3);
            float v0 = __uint_as_float((unsigned)__shfl(cv.y, s0));
            float v1 = __uint_as_float((unsigned)__shfl(cv.y, s1));
            float v2 = __uint_as_float((unsigned)__shfl(cv.y, s2));
            float v3 = __uint_as_float((unsigned)__shfl(cv.y, s3));
            float4 g0 = *(const float4*)(egoPrev + (size_t)c0 * OUTC + dgo);
            float4 g1 = *(const float4*)(egoPrev + (size_t)c1 * OUTC + dgo);
            float4 g2 = *(const float4*)(egoPrev + (size_t)c2 * OUTC + dgo);
            float4 g3 = *(const float4*)(egoPrev + (size_t)c3 * OUTC + dgo);
            acc.x = fmaf(v0, g0.x, acc.x); acc.y = fmaf(v0, g0.y, acc.y);
            acc.z = fmaf(v0, g0.z, acc.z); acc.w = fmaf(v0, g0.w, acc.w);
            acc.x = fmaf(v1, g1.x, acc.x); acc.y = fmaf(v1, g1.y, acc.y);
            acc.z = fmaf(v1, g1.z, acc.z); acc.w = fmaf(v1, g1.w, acc.w);
            acc.x = fmaf(v2, g2.x, acc.x); acc.y = fmaf(v2, g2.y, acc.y);
            acc.z = fmaf(v2, g2.z, acc.z); acc.w = fmaf(v2, g2.w, acc.w);
            acc.x = fmaf(v3, g3.x, acc.x); acc.y = fmaf(v3, g3.y, acc.y);
            acc.z = fmaf(v3, g3.z, acc.z); acc.w = fmaf(v3, g3.w, acc.w);
        }
    }
    // reduce the 4 edge-subgroups: lanes {l, l^16, l^32, l^48} hold same dims
    acc.x += __shfl_xor(acc.x, 16); acc.y += __shfl_xor(acc.y, 16);
    acc.z += __shfl_xor(acc.z, 16); acc.w += __shfl_xor(acc.w, 16);
    acc.x += __shfl_xor(acc.x, 32); acc.y += __shfl_xor(acc.y, 32);
    acc.z += __shfl_xor(acc.z, 32); acc.w += __shfl_xor(acc.w, 32);
    // redistribute: lane j wants dim j = element (j&3) of group (j>>2)
    int srcl = lane >> 2;
    float t0 = __shfl(acc.x, srcl), t1 = __shfl(acc.y, srcl);
    float t2 = __shfl(acc.z, srcl), t3 = __shfl(acc.w, srcl);
    int e2 = lane & 3;
    float sv = (e2 == 0) ? t0 : (e2 == 1) ? t1 : (e2 == 2) ? t2 : t3;

    // dense epilogue: 4 split accumulators per output (dep chain 16)
    float eg = egoPrev[(size_t)row * OUTC + lane];
    float p  = sv * eg;
    float ag0 = biasg, ag1 = 0.f, ag2 = 0.f, ag3 = 0.f;
    float ab0 = biasb, ab1 = 0.f, ab2 = 0.f, ab3 = 0.f;
    #pragma unroll
    for (int k = 0; k < 64; k += 4) {
        float sk0 = __shfl(sv, k),     pk0 = __shfl(p, k);
        float sk1 = __shfl(sv, k + 1), pk1 = __shfl(p, k + 1);
        float sk2 = __shfl(sv, k + 2), pk2 = __shfl(p, k + 2);
        float sk3 = __shfl(sv, k + 3), pk3 = __shfl(p, k + 3);
        ag0 = fmaf(sk0, WgT[(k)     * 65 + lane], ag0);
        ag1 = fmaf(sk1, WgT[(k + 1) * 65 + lane], ag1);
        ag2 = fmaf(sk2, WgT[(k + 2) * 65 + lane], ag2);
        ag3 = fmaf(sk3, WgT[(k + 3) * 65 + lane], ag3);
        ab0 = fmaf(pk0, WbT[(k)     * 65 + lane], ab0);
        ab1 = fmaf(pk1, WbT[(k + 1) * 65 + lane], ab1);
        ab2 = fmaf(pk2, WbT[(k + 2) * 65 + lane], ab2);
        ab3 = fmaf(pk3, WbT[(k + 3) * 65 + lane], ab3);
    }
    float accg = (ag0 + ag1) + (ag2 + ag3);
    float accb = (ab0 + ab1) + (ab2 + ab3);
    accg = (accg > 0.f) ? accg : NEG_SLOPE * accg;
    accb = (accb > 0.f) ? accb : NEG_SLOPE * accb;
    egoNew[(size_t)row * OUTC + lane] = accg + accb;
}

extern "C" void kernel_launch(void* const* d_in, const int* in_sizes, int n_in,
                              void* d_out, int out_size, void* d_ws, size_t ws_size,
                              hipStream_t stream) {
    const int*   ui   = (const int*)  d_in[0];
    const int*   ii   = (const int*)  d_in[1];
    const int*   rows = (const int*)  d_in[2];
    const int*   cols = (const int*)  d_in[3];
    const float* vals = (const float*)d_in[4];
    const float* uemb = (const float*)d_in[5];
    const float* iemb = (const float*)d_in[6];
    const float* Wg0 = (const float*)d_in[7],  *bg0 = (const float*)d_in[8];
    const float* Wb0 = (const float*)d_in[9],  *bb0 = (const float*)d_in[10];
    const float* Wg1 = (const float*)d_in[11], *bg1 = (const float*)d_in[12];
    const float* Wb1 = (const float*)d_in[13], *bb1 = (const float*)d_in[14];
    float* out = (float*)d_out;

    char* ws = (char*)d_ws;
    int2*  csr    = (int2*)ws; ws += (size_t)NEDGES * 8;
    int*   pos    = (int*) ws; ws += (size_t)NEDGES * 4;
    int*   rowptr = (int*) ws; ws += (size_t)(NNODES + 1) * 4;
    int*   counts = (int*) ws; ws += (size_t)NNODES * 4;
    int*   blksum = (int*) ws; ws += 256 * 4;

    const int NBLK = (NNODES + 1023) / 1024;  // 147

    // ego0 -> out cols [0,64)
    build_ego<<<(NNODES * 16 + 255) / 256, 256, 0, stream>>>(ui, ii, uemb, iemb, out);

    // CSR build (once, reused for both layers)
    hipMemsetAsync(counts, 0, (size_t)NNODES * 4, stream);
    count_pos<<<(NEDGES + 255) / 256, 256, 0, stream>>>(rows, counts, pos);
    scan_chunk<<<NBLK, 1024, 0, stream>>>(counts, rowptr, blksum, NNODES);
    scan_sums<<<1, 256, 0, stream>>>(blksum, NBLK);
    add_offsets<<<NBLK, 1024, 0, stream>>>(rowptr, blksum, NNODES);
    fill_csr<<<(NEDGES + 255) / 256, 256, 0, stream>>>(rows, cols, vals, pos, rowptr, csr);

    // layer 0: ego1 -> out cols [64,128)
    spmm_fused<<<(NNODES + 7) / 8, 512, 0, stream>>>(rowptr, csr, out + 0, out + 64,
                                                     Wg0, bg0, Wb0, bb0);
    // layer 1: ego2 -> out cols [128,192)
    spmm_fused<<<(NNODES + 7) / 8, 512, 0, stream>>>(rowptr, csr, out + 64, out + 128,
                                                     Wg1, bg1, Wb1, bb1);
}